// Round 8
// baseline (3200.876 us; speedup 1.0000x reference)
//
#include <hip/hip_runtime.h>

#define BB   32
#define TT   2048
#define HH   256
#define G3   768      // 3*H
#define NVOC 18       // vocab rows (V+2)
#define NOUT 17       // head outputs (V+1)
#define LOGITS_ELEMS ((size_t)BB * TT * NOUT)

// LDS pad: keep static LDS > 160KB/2 so at most 1 block/CU is possible ->
// allocator's occupancy target is 16 waves/CU = 4 waves/EU = 128-reg budget,
// exactly matching this kernel's design point (96 weight + ~30 working regs).
#define TOKPAD 4608   // (2048+4608)*4 = 26624 B; total LDS 82944 B > 81920 B

typedef _Float16 h2 __attribute__((ext_vector_type(2)));

__device__ __forceinline__ float bf1(unsigned short u){
  union{unsigned int i; float f;} v; v.i = ((unsigned int)u) << 16; return v.f;
}
__device__ __forceinline__ unsigned short f2bf(float f){
  union{float f; unsigned int i;} v; v.f = f;
  unsigned int lsb = (v.i >> 16) & 1u;
  v.i += 0x7fffu + lsb;               // round-to-nearest-even
  return (unsigned short)(v.i >> 16);
}

__device__ __forceinline__ float ld1(const float* p, size_t i){ return p[i]; }
__device__ __forceinline__ float ld1(const unsigned short* p, size_t i){ return bf1(p[i]); }

// Device-side dtype detection: W_ih ~ uniform(-1/16,1/16). If the buffer is
// f32, low-half words decode as bf16 with random exponents -> some |v|>0.25.
__device__ __forceinline__ bool detect_f32(const void* W_ih_raw){
  const unsigned short* u = (const unsigned short*)W_ih_raw;
  bool big = false;
  #pragma unroll
  for (int i = 0; i < 64; i++){
    float v = bf1(u[i]);
    big |= !(v >= -0.25f && v <= 0.25f);
  }
  return big;
}

#if __has_builtin(__builtin_amdgcn_fdot2)
#define FDOT2(a,b,c) __builtin_amdgcn_fdot2((a),(b),(c),false)
#else
#define FDOT2(a,b,c) ((c) + (float)(a).x*(float)(b).x + (float)(a).y*(float)(b).y)
#endif

__device__ __forceinline__ h2 bch2(unsigned int u){ return __builtin_bit_cast(h2, u); }
__device__ __forceinline__ h2 bch2f(float f){ return __builtin_bit_cast(h2, f); }

// DPP quad shuffles (pure VALU, no LDS round-trip)
__device__ __forceinline__ float dppB1(float v){    // quad_perm(1,0,3,2): xor1
  int i = __builtin_bit_cast(int, v);
  i = __builtin_amdgcn_mov_dpp(i, 0xB1, 0xF, 0xF, true);
  return __builtin_bit_cast(float, i);
}
__device__ __forceinline__ float dpp4E(float v){    // quad_perm(2,3,0,1): xor2
  int i = __builtin_bit_cast(int, v);
  i = __builtin_amdgcn_mov_dpp(i, 0x4E, 0xF, 0xF, true);
  return __builtin_bit_cast(float, i);
}

// raw barrier: LDS-visibility only. Skips __syncthreads()'s vmcnt(0) drain so
// per-step global stores (outs/betas, never read back in-kernel) stay
// fire-and-forget instead of stalling every iteration.
__device__ __forceinline__ void bar_lds(){
  asm volatile("s_waitcnt lgkmcnt(0)\n\ts_barrier" ::: "memory");
}

// ---------------------------------------------------------------------------
// k_prep: pack W_hh for k_scan's 1024-thread quad-per-unit layout.
// k_scan thread tid (u = tid>>2, lq = tid&3) owns hidden unit u for all 3
// gates, k-range [64lq, 64lq+64).  Weight reg (g, jx), g in {r,z,n}=0,1,2,
// jx = 0..7: float4 of 4 h2 k-pairs; pair c = ( W_hh[k0+2c][col],
// W_hh[k0+2c+1][col] ), k0 = 64lq + 8jx, col = 256g + u.
// Flat: Wp4[(g*8 + jx)*1024 + tid]; prep thread s (96x256 grid) writes Wp4[s].
// ---------------------------------------------------------------------------
template<typename T>
__device__ __forceinline__ void prep_body(const T* W_hh, float4* Wp4){
  int s   = blockIdx.x * 256 + threadIdx.x;    // 0..24575
  int tid = s & 1023;
  int r10 = s >> 10;                           // 0..23
  int jx  = r10 & 7, g = r10 >> 3;             // g 0..2
  int u   = tid >> 2, lq = tid & 3;
  int col = (g << 8) + u;
  int k0  = (lq << 6) + (jx << 3);
  float c0, c1, c2, c3;
  #pragma unroll
  for (int c = 0; c < 4; c++){
    h2 pr;
    pr.x = (_Float16)ld1(W_hh, (size_t)(k0 + 2*c    ) * G3 + col);
    pr.y = (_Float16)ld1(W_hh, (size_t)(k0 + 2*c + 1) * G3 + col);
    float fc = __builtin_bit_cast(float, pr);
    if (c == 0) c0 = fc; else if (c == 1) c1 = fc;
    else if (c == 2) c2 = fc; else c3 = fc;
  }
  float4 v; v.x = c0; v.y = c1; v.z = c2; v.w = c3;
  Wp4[s] = v;
}

__global__ __launch_bounds__(256) void k_prep(
    const void* __restrict__ W_hh, const void* __restrict__ W_ih,
    float4* __restrict__ Wp4)
{
  if (detect_f32(W_ih)) prep_body<float>((const float*)W_hh, Wp4);
  else                  prep_body<unsigned short>((const unsigned short*)W_hh, Wp4);
}

// ---------------------------------------------------------------------------
// k_proj: proj[v][j] = b_ih[j] + sum_k embed[v][k]*W_ih[k][j]. Block = one v,
// 768 threads, coalesced W_ih reads. Block 0 also converts b_hh -> f32 bb[].
// ---------------------------------------------------------------------------
template<typename T>
__device__ __forceinline__ void proj_body(const T* embed, const T* W_ih,
                                          const T* b_ih, const T* b_hh,
                                          float* proj, float* bb){
  __shared__ float s_e[HH];
  int v = blockIdx.x, j = threadIdx.x;
  if (j < HH) s_e[j] = ld1(embed, (size_t)v * HH + j);
  if (v == 0) bb[j] = ld1(b_hh, (size_t)j);
  __syncthreads();
  float acc = ld1(b_ih, (size_t)j);
  #pragma unroll 8
  for (int k = 0; k < HH; k++)
    acc += s_e[k] * ld1(W_ih, (size_t)k * G3 + j);
  proj[(size_t)v * G3 + j] = acc;
}

__global__ __launch_bounds__(768) void k_proj(
    const void* __restrict__ embed, const void* __restrict__ W_ih,
    const void* __restrict__ b_ih, const void* __restrict__ b_hh,
    float* __restrict__ proj, float* __restrict__ bb)
{
  if (detect_f32(W_ih))
    proj_body<float>((const float*)embed, (const float*)W_ih,
                     (const float*)b_ih, (const float*)b_hh, proj, bb);
  else
    proj_body<unsigned short>((const unsigned short*)embed,
                              (const unsigned short*)W_ih,
                              (const unsigned short*)b_ih,
                              (const unsigned short*)b_hh, proj, bb);
}

// ---------------------------------------------------------------------------
// k_scan: GRU scan, 1024 threads (16 waves), one block per batch element.
// Quad (lanes 4u..4u+3) owns hidden unit u; lane lq covers k in
// [64lq, 64lq+64) for all 3 gates: 96 fdot2/thread, 24 float4 weights
// (96 VGPRs).  WHY 1024 THREADS: a 1024-thread block pool-caps total regs
// at 128/wave (4 waves/SIMD x 128 = 512 pool).  96 weights + ~30 working
// fits ENTIRELY in arch VGPRs, so the allocator has no pressure reason to
// park weights in AGPRs and pay a v_accvgpr_read per dword per step -- the
// failure mode of every 512-thread variant (r2-r6: 192-dword file, arch
// demand > budget, ~192 read instr/thread/step; confirmed by r7's asm
// showing weights assigned to a34/a64).
// Quad DPP reduce (xor1+xor2) -> all 4 lanes hold full ar/az/an; gate chain
// redundant per lane; lq0 publishes s_h (b16, swizzled), lq1 stores outs,
// lq2 stores beta.  One lgkm-only barrier per step; s_h double-buffered +
// XOR line-swizzled (4 k-quarter lines -> disjoint bank quads).
// ---------------------------------------------------------------------------

#define FORJX1(M, g, base) \
  M(g,0,(base)+0) M(g,1,(base)+1) M(g,2,(base)+2) M(g,3,(base)+3) \
  M(g,4,(base)+4) M(g,5,(base)+5) M(g,6,(base)+6) M(g,7,(base)+7)
#define FORALLW(M) FORJX1(M,r,0) FORJX1(M,z,8) FORJX1(M,n,16)

#define DECLW(g,jx,idx) float4 w_##g##_##jx = wp[(idx)*1024];

#define DOTC(jx, c, hcomp) { \
  h2 xx = bch2((unsigned)(hcomp)); \
  ar = FDOT2(bch2f(w_r_##jx.c), xx, ar); \
  az = FDOT2(bch2f(w_z_##jx.c), xx, az); \
  an = FDOT2(bch2f(w_n_##jx.c), xx, an); }

#define DOTJ(jx) { \
  int4 hv = hp[hix##jx]; \
  DOTC(jx, x, hv.x) DOTC(jx, y, hv.y) DOTC(jx, z, hv.z) DOTC(jx, w, hv.w) }

__global__ __launch_bounds__(1024, 4) void k_scan(
    const int*    __restrict__ tokens,
    const float4* __restrict__ Wp4,    // prepped weights
    const float*  __restrict__ bb,     // b_hh as f32
    const void*   __restrict__ W_ih,   // dtype detection (betas store)
    const float*  __restrict__ proj,
    _Float16*     __restrict__ outs,   // [B,T,H] f16 scratch
    void*         __restrict__ d_out_base)
{
  __shared__ float s_proj[NVOC * G3];            // 55296 B
  __shared__ int   s_tok[TT + TOKPAD];           // 26624 B (18KB = occupancy pad)
  __shared__ __align__(16) _Float16 s_h[2][HH];  //  1024 B dbuf h (swizzled)
  // total static LDS = 82944 B > 81920 B -> at most 1 block/CU

  const bool f32m = detect_f32(W_ih);
  const int b   = blockIdx.x;
  const int tid = threadIdx.x;     // 0..1023
  const int u   = tid >> 2;        // hidden unit 0..255
  const int lq  = tid & 3;         // k-quarter

  // stage proj (3456 float4) and tokens (512 int4); zero both h buffers
  for (int i = tid; i < NVOC * G3 / 4; i += 1024)
    ((float4*)s_proj)[i] = ((const float4*)proj)[i];
  if (tid < 512) ((int4*)s_tok)[tid] = ((const int4*)(tokens + (size_t)b * TT))[tid];
  if (tid < 256) ((int*)s_h)[tid] = 0;

  // 24 float4 weight registers (96 VGPRs) -- fits arch budget, no AGPR tax
  const float4* wp = Wp4 + tid;
  FORALLW(DECLW)

  // biases for this quad's unit
  const float bhr = bb[u];
  const float bhz = bb[HH + u];
  const float bhn = bb[2*HH + u];

  // swizzle: logical 16B line L (of 32 per buffer) lives at physical line
  // (L&24) | ((L&7) ^ (L>>3)).  Reader line for (lq,jx): L = 8lq+jx ->
  // phys = 8lq | (jx^lq).  Writer (unit u, b16): L = u>>3, in-line slot u&7:
  const int hb = lq << 3;
  const int hix0 = hb | (0 ^ lq), hix1 = hb | (1 ^ lq), hix2 = hb | (2 ^ lq),
            hix3 = hb | (3 ^ lq), hix4 = hb | (4 ^ lq), hix5 = hb | (5 ^ lq),
            hix6 = hb | (6 ^ lq), hix7 = hb | (7 ^ lq);
  int pu;   // physical f16 index for s_h write of unit u
  {
    int L = u >> 3;
    int P = (L & 24) | ((L & 7) ^ (L >> 3));
    pu = P * 8 + (u & 7);
  }

  float h_old = 0.f;               // h[u] (all 4 lanes hold it)

  // per-lane store stream: lq1 -> outs f16; lq2 -> beta (bf16 or f32)
  char* sp;
  int   sstride;
  if (lq == 1) {
    sp = (char*)(outs + (size_t)b * TT * HH + u);
    sstride = HH * 2;
  } else if (lq == 2) {
    if (f32m) { sp = (char*)((float*)d_out_base + LOGITS_ELEMS
                             + (size_t)b * TT * HH + u); sstride = HH * 4; }
    else      { sp = (char*)((unsigned short*)d_out_base + LOGITS_ELEMS
                             + (size_t)b * TT * HH + u); sstride = HH * 2; }
  } else {
    sp = (char*)(outs);            // unused
    sstride = 0;
  }

  __syncthreads();   // staging + weight loads settled (one-time full drain)

  for (int t = 0; t < TT; t++) {
    int tok = s_tok[t];
    const float* pj = s_proj + tok * G3;
    float gir = pj[u];
    float giz = pj[HH + u];
    float gin = pj[2*HH + u];

    const int4* hp = (const int4*)(&s_h[t & 1][0]);

    float ar = 0.f, az = 0.f, an = 0.f;
    DOTJ(0) DOTJ(1) DOTJ(2) DOTJ(3) DOTJ(4) DOTJ(5) DOTJ(6) DOTJ(7)

    // quad reduction: xor1 then xor2 -> every lane holds the full sums
    ar += dppB1(ar);  az += dppB1(az);  an += dppB1(an);
    ar += dpp4E(ar);  az += dpp4E(az);  an += dpp4E(an);

    // gate chain (redundant across the quad's 4 lanes -- same wave cost)
    float r = 1.f / (1.f + __expf(-(gir + ar + bhr)));
    float z = 1.f / (1.f + __expf(-(giz + az + bhz)));
    float x = gin + r * (an + bhn);
    x = fminf(fmaxf(x, -15.f), 15.f);
    float e = __expf(2.f * x);
    float n = (e - 1.f) / (e + 1.f);     // tanh
    float hn = (1.f - z) * n + z * h_old;
    h_old = hn;

    if (lq == 0) {                        // publish h[u] (swizzled b16)
      ((_Float16*)(&s_h[(t + 1) & 1][0]))[pu] = (_Float16)hn;
    } else if (lq == 1) {                 // outs f16
      *(_Float16*)sp = (_Float16)hn;
    } else if (lq == 2) {                 // beta
      if (f32m) *(float*)sp = z;
      else      *(unsigned short*)sp = f2bf(z);
    }
    sp += sstride;
    bar_lds();   // lgkmcnt(0)+s_barrier; global stores stay in flight
  }
}

// ---------------------------------------------------------------------------
// k_head: logits = outs @ W_head + b_head.  outs is f16; W_head staged to LDS
// as packed h2 pairs (stride 129 h2 per output column -> no bank conflicts),
// inner loop is 128 fdot2.
// ---------------------------------------------------------------------------
#define WSTR 129

template<typename T>
__device__ __forceinline__ void stage_head(const T* W_head, const T* b_head,
                                           h2* s_w, float* s_b, int tid){
  for (int i = tid; i < NOUT * 128; i += 256) {
    int o = i >> 7, ip = i & 127;
    h2 pr;
    pr.x = (_Float16)ld1(W_head, (size_t)(2*ip    ) * NOUT + o);
    pr.y = (_Float16)ld1(W_head, (size_t)(2*ip + 1) * NOUT + o);
    s_w[o * WSTR + ip] = pr;
  }
  if (tid < NOUT) s_b[tid] = ld1(b_head, (size_t)tid);
}

__global__ __launch_bounds__(256) void k_head(
    const _Float16* __restrict__ outs,
    const void* __restrict__ W_head,
    const void* __restrict__ b_head,
    const void* __restrict__ W_ih,
    void* __restrict__ logits_out)
{
  __shared__ h2 s_w[NOUT * WSTR];
  __shared__ float s_b[NOUT];
  const bool f32m = detect_f32(W_ih);
  const int tid = threadIdx.x;

  if (f32m) stage_head<float>((const float*)W_head, (const float*)b_head,
                              s_w, s_b, tid);
  else      stage_head<unsigned short>((const unsigned short*)W_head,
                                       (const unsigned short*)b_head,
                                       s_w, s_b, tid);
  __syncthreads();

  size_t gid = (size_t)blockIdx.x * 256 + tid;
  if (gid >= LOGITS_ELEMS) return;
  int o = (int)(gid % NOUT);
  size_t row = gid / NOUT;

  const uint4* xp = (const uint4*)(outs + row * HH);
  const h2* wv = s_w + o * WSTR;
  float a0 = 0.f, a1 = 0.f, a2 = 0.f, a3 = 0.f;
  #pragma unroll 8
  for (int kk = 0; kk < 32; kk++) {
    uint4 uu = xp[kk];
    int kb = kk * 4;
    a0 = FDOT2(bch2(uu.x), wv[kb+0], a0);
    a1 = FDOT2(bch2(uu.y), wv[kb+1], a1);
    a2 = FDOT2(bch2(uu.z), wv[kb+2], a2);
    a3 = FDOT2(bch2(uu.w), wv[kb+3], a3);
  }
  float val = ((a0 + a1) + (a2 + a3)) + s_b[o];
  if (f32m) ((float*)logits_out)[gid] = val;
  else      ((unsigned short*)logits_out)[gid] = f2bf(val);
}

// ---------------------------------------------------------------------------
extern "C" void kernel_launch(void* const* d_in, const int* in_sizes, int n_in,
                              void* d_out, int out_size, void* d_ws, size_t ws_size,
                              hipStream_t stream)
{
  // inputs: tokens, embed, W_ih, W_hh, b_ih, b_hh, W_head, b_head
  const int* tokens = (const int*)d_in[0];
  const void* embed  = d_in[1];
  const void* W_ih   = d_in[2];
  const void* W_hh   = d_in[3];
  const void* b_ih   = d_in[4];
  const void* b_hh   = d_in[5];
  const void* W_head = d_in[6];
  const void* b_head = d_in[7];

  // workspace layout (16B aligned):
  // proj: 13824 f32 = 55296 B | bb: 768 f32 = 3072 B | Wp: 24576 float4 = 393216 B | outs (f16)
  char* ws = (char*)d_ws;
  float*    proj = (float*)ws;
  float*    bb   = (float*)(ws + 55296);
  float4*   Wp4  = (float4*)(ws + 55296 + 3072);
  _Float16* outs = (_Float16*)(ws + 55296 + 3072 + 393216);

  k_prep<<<96, 256, 0, stream>>>(W_hh, W_ih, Wp4);
  k_proj<<<NVOC, G3, 0, stream>>>(embed, W_ih, b_ih, b_hh, proj, bb);
  k_scan<<<BB, 1024, 0, stream>>>(tokens, Wp4, bb, W_ih, proj, outs, d_out);
  k_head<<<(int)((LOGITS_ELEMS + 255) / 256), 256, 0, stream>>>(
      outs, W_head, b_head, W_ih, d_out);
}